// Round 9
// baseline (236.303 us; speedup 1.0000x reference)
//
#include <hip/hip_runtime.h>
#include <hip/hip_bf16.h>

#define BB 2
#define CC 128
#define NN 4096
#define KK 20

// workspace offsets, in floats
#define WS_FCACC  16
#define WS_FS     1024
#define WS_X      8192
#define WS_XX     32768
#define WS_P      65536
#define WS_Q      1114112
#define WS_FE     2326528
#define WS_F12    3375104

struct InPtrs { const void* p[22]; };

__device__ __forceinline__ int detect_bf16(const void* xyz) {
  const unsigned* u = (const unsigned*)xyz;
  int cnt = 0;
  for (int i = 0; i < 64; ++i) {
    unsigned lo = u[i] & 0x7FFFu;
    cnt += (lo >= 0x3C00u && lo <= 0x4100u) ? 1 : 0;
  }
  return cnt >= 32;
}

__device__ __forceinline__ float ldin(const void* p, long long i, int flag) {
  if (flag) {
    unsigned short b = ((const unsigned short*)p)[i];
    return __uint_as_float(((unsigned)b) << 16);
  }
  return ((const float*)p)[i];
}

// f64 key: (sortable32(pd) << 12) | (4095 - m), exact integer <= 2^44.
// Higher key = larger pd, ties broken toward lower index m (matches lax.top_k).
__device__ __forceinline__ double dkey(float v, int m) {
  unsigned u = __float_as_uint(v);
  u = (u & 0x80000000u) ? ~u : (u | 0x80000000u);
  return (double)u * 4096.0 + (double)((NN - 1) - m);
}

__device__ __forceinline__ void insert4d(double key,
    double& a0, double& a1, double& a2, double& a3) {
  bool b0 = key > a0, b1 = key > a1, b2 = key > a2, b3 = key > a3;
  a3 = b3 ? (b2 ? a2 : key) : a3;
  a2 = b2 ? (b1 ? a1 : key) : a2;
  a1 = b1 ? (b0 ? a0 : key) : a1;
  a0 = b0 ? key : a0;
}

// ---------------- k1: X/XX convert + P,Q projections (all inputs inline) ------
// 256 blocks; block = 32 points; wave w covers o in [w*16,w*16+16);
// sub=(t>>5)&1 -> o-subrange sub*8..+8; mloc = t&31 is the point.
__global__ __launch_bounds__(256) void k1_pq(InPtrs in, float* ws) {
  __shared__ float ldsW[64 * 128];   // staged W2 half  (32 KB)
  __shared__ float ldsF[64 * 32];    // staged F half   (8 KB)
  __shared__ float sS1[64], sC1[64], sS2[64], sC2[64], sW1[384];
  int flag = detect_bf16(in.p[0]);
  int t = threadIdx.x;
  int bid = blockIdx.x;
  // --- prologue A: grid-stride X convert + XX (blocks 0..31 active) ---
  {
    int gid = bid * 256 + t;
    if (gid < BB * NN) {
      int b = gid >> 12, m = gid & (NN - 1);
      long long xb = (long long)b * 3 * NN;
      float x0 = ldin(in.p[0], xb + m, flag);
      float x1 = ldin(in.p[0], xb + NN + m, flag);
      float x2 = ldin(in.p[0], xb + 2 * NN + m, flag);
      ws[WS_X + xb + m] = x0;
      ws[WS_X + xb + NN + m] = x1;
      ws[WS_X + xb + 2 * NN + m] = x2;
      ws[WS_XX + gid] =
        __fadd_rn(__fadd_rn(__fmul_rn(x0, x0), __fmul_rn(x1, x1)), __fmul_rn(x2, x2));
    }
    if (bid == 0 && t < 16) ws[WS_FCACC + t] = 0.f;   // zero accum for k23 atomics
  }
  // --- prologue B: fold BN constants + stage W1 into LDS ---
  if (t < 64) {
    float g1 = ldin(in.p[4], t, flag), v1 = ldin(in.p[7], t, flag);
    float s1 = g1 / sqrtf(v1 + 1e-5f);
    float b1 = ldin(in.p[3], t, flag), be1 = ldin(in.p[5], t, flag), m1v = ldin(in.p[6], t, flag);
    sS1[t] = s1; sC1[t] = s1 * (b1 - m1v) + be1;
    float g2 = ldin(in.p[10], t, flag), v2 = ldin(in.p[13], t, flag);
    float s2 = g2 / sqrtf(v2 + 1e-5f);
    float b2 = ldin(in.p[9], t, flag), be2 = ldin(in.p[11], t, flag), m2v = ldin(in.p[12], t, flag);
    sS2[t] = s2; sC2[t] = s2 * (b2 - m2v) + be2;
  }
  for (int i = t; i < 384; i += 256) sW1[i] = ldin(in.p[2], i, flag);
  // --- main GEMM: two c-halves, W2+F staged from inputs ---
  int b = bid >> 7;
  int m0 = (bid & 127) << 5;
  int w = t >> 6, sub = (t >> 5) & 1, mloc = t & 31;
  const void* Fin = in.p[1];
  const void* W2in = in.p[8];
  long long fb = (long long)b * CC * NN;
  float accP[8], accQ[8];
#pragma unroll
  for (int j = 0; j < 8; ++j) { accP[j] = 0.f; accQ[j] = 0.f; }
  for (int half = 0; half < 2; ++half) {
    if (half) __syncthreads();
    for (int i = t; i < 64 * 128; i += 256) {
      int o = i >> 7, r = i & 127;
      int c = (r & 63) + half * 64 + ((r >> 6) << 7);   // +128 selects Q columns
      ldsW[i] = ldin(W2in, o * 256 + c, flag);
    }
    for (int i = t; i < 64 * 32; i += 256) {
      int cl = i >> 5, ml = i & 31;
      ldsF[i] = ldin(Fin, fb + (long long)(half * 64 + cl) * NN + m0 + ml, flag);
    }
    __syncthreads();
    for (int cl = 0; cl < 64; ++cl) {
      float f = ldsF[cl * 32 + mloc];
#pragma unroll
      for (int j = 0; j < 8; ++j) {
        int o = w * 16 + sub * 8 + j;
        accP[j] = fmaf(ldsW[o * 128 + cl], f, accP[j]);
        accQ[j] = fmaf(ldsW[o * 128 + 64 + cl], f, accQ[j]);
      }
    }
  }
  // --- epilogue: xyz part + BN fold, write P/Q ---
  int m = m0 + mloc;
  long long xb = (long long)b * 3 * NN;
  float x0 = ldin(in.p[0], xb + m, flag);
  float x1 = ldin(in.p[0], xb + NN + m, flag);
  float x2 = ldin(in.p[0], xb + 2 * NN + m, flag);
  float* P = ws + WS_P + ((long long)(b * NN + m)) * 128;
  float* Q = ws + WS_Q + ((long long)(b * NN + m)) * 128;
#pragma unroll
  for (int j = 0; j < 8; ++j) {
    int o = w * 16 + sub * 8 + j;
    float s1 = sS1[o], c1 = sC1[o];
    float px = fmaf(sW1[o * 6 + 2], x2, fmaf(sW1[o * 6 + 1], x1, sW1[o * 6 + 0] * x0));
    float qx = fmaf(sW1[o * 6 + 5], x2, fmaf(sW1[o * 6 + 4], x1, sW1[o * 6 + 3] * x0));
    P[o] = s1 * px;
    Q[o] = fmaf(s1, qx - px, c1);
    float s2 = sS2[o], c2 = sC2[o];
    P[64 + o] = s2 * accP[j];
    Q[64 + o] = fmaf(s2, accQ[j] - accP[j], c2);
  }
}

// ------- k23: KNN top-20 (2 points per wave) + gather/max-pool + down-proj ----
__global__ __launch_bounds__(256) void k23_knn_fenc_down(InPtrs in, float* ws) {
  __shared__ float ldsW[32 * 129];   // WD1|WD2 staged (16.5 KB)
  __shared__ float ldsFE[8 * 128];   // 4 KB
  __shared__ float ldsFC[16];
  int flag = detect_bf16(in.p[0]);
  int t = threadIdx.x;
  int w = t >> 6, lane = t & 63;
  int pt0 = blockIdx.x * 8 + w * 2;           // 1024 blocks, 1 wave = 2 points
  int b = pt0 >> 12;
  int nA = pt0 & (NN - 1);
  int nB = nA + 1;
  // stage down-proj weights (consumed after the post-FE barrier)
  for (int i = t; i < 32 * 128; i += 256) {
    int o = i >> 7, c = i & 127;
    ldsW[o * 129 + c] = (o < 16) ? ldin(in.p[14], o * 128 + c, flag)
                                 : ldin(in.p[15], (o - 16) * 128 + c, flag);
  }
  if (t < 16) ldsFC[t] = 0.f;
  // ---- KNN core: two interleaved instances of the round-7-verified logic ----
  const float* X = ws + WS_X + (long long)b * 3 * NN;
  const float* XX = ws + WS_XX + (long long)b * NN;
  float xA0 = X[nA], xA1 = X[NN + nA], xA2 = X[2 * NN + nA], xxA = XX[nA];
  float xB0 = X[nB], xB1 = X[NN + nB], xB2 = X[2 * NN + nB], xxB = XX[nB];
  double aA0 = -1.0, aA1 = -1.0, aA2 = -1.0, aA3 = -1.0;
  double aB0 = -1.0, aB1 = -1.0, aB2 = -1.0, aB3 = -1.0;
#pragma unroll 4
  for (int s = 0; s < 64; ++s) {
    int m = s * 64 + lane;
    float c0 = X[m], c1 = X[NN + m], c2 = X[2 * NN + m], xxm = XX[m];
    float inA = __fadd_rn(__fadd_rn(__fmul_rn(c0, xA0), __fmul_rn(c1, xA1)), __fmul_rn(c2, xA2));
    float pdA = __fsub_rn(__fsub_rn(__fmul_rn(2.0f, inA), xxA), xxm);
    float inB = __fadd_rn(__fadd_rn(__fmul_rn(c0, xB0), __fmul_rn(c1, xB1)), __fmul_rn(c2, xB2));
    float pdB = __fsub_rn(__fsub_rn(__fmul_rn(2.0f, inB), xxB), xxm);
    insert4d(dkey(pdA, m), aA0, aA1, aA2, aA3);
    insert4d(dkey(pdB, m), aB0, aB1, aB2, aB3);
  }
  unsigned long long usedA = 0, usedB = 0;
  int nvA = 4, nvB = 4;
  double winA = 0.0, winB = 0.0;              // lane r keeps round-r winners
  for (int r = 0; r < KK; ++r) {
    double vA = aA0, vB = aB0;
#pragma unroll
    for (int off = 1; off < 64; off <<= 1) {
      double tA = __shfl_xor(vA, off);
      double tB = __shfl_xor(vB, off);
      vA = fmax(vA, tA);
      vB = fmax(vB, tB);
    }
    if (lane == r) { winA = vA; winB = vB; }
    if (aA0 == vA) {                          // unique owner (idx embedded in key)
      unsigned hi = (unsigned)(vA * (1.0 / 4096.0));
      double rem = vA - 4096.0 * (double)hi;
      int mm = (NN - 1) - (int)rem;
      usedA |= 1ull << (mm >> 6);
      aA0 = aA1; aA1 = aA2; aA2 = aA3; aA3 = -1.0; --nvA;
      if (nvA == 0) {                         // rare: lane supplied >=5 winners
        aA0 = aA1 = aA2 = aA3 = -1.0;
#pragma unroll 1
        for (int s = 0; s < 64; ++s) {
          if (!((usedA >> s) & 1ull)) {
            int m = s * 64 + lane;
            float c0 = X[m], c1 = X[NN + m], c2 = X[2 * NN + m], xxm = XX[m];
            float inr = __fadd_rn(__fadd_rn(__fmul_rn(c0, xA0), __fmul_rn(c1, xA1)), __fmul_rn(c2, xA2));
            float pd = __fsub_rn(__fsub_rn(__fmul_rn(2.0f, inr), xxA), xxm);
            insert4d(dkey(pd, m), aA0, aA1, aA2, aA3);
          }
        }
        nvA = 4;
      }
    }
    if (aB0 == vB) {
      unsigned hi = (unsigned)(vB * (1.0 / 4096.0));
      double rem = vB - 4096.0 * (double)hi;
      int mm = (NN - 1) - (int)rem;
      usedB |= 1ull << (mm >> 6);
      aB0 = aB1; aB1 = aB2; aB2 = aB3; aB3 = -1.0; --nvB;
      if (nvB == 0) {
        aB0 = aB1 = aB2 = aB3 = -1.0;
#pragma unroll 1
        for (int s = 0; s < 64; ++s) {
          if (!((usedB >> s) & 1ull)) {
            int m = s * 64 + lane;
            float c0 = X[m], c1 = X[NN + m], c2 = X[2 * NN + m], xxm = XX[m];
            float inr = __fadd_rn(__fadd_rn(__fmul_rn(c0, xB0), __fmul_rn(c1, xB1)), __fmul_rn(c2, xB2));
            float pd = __fsub_rn(__fsub_rn(__fmul_rn(2.0f, inr), xxB), xxm);
            insert4d(dkey(pd, m), aB0, aB1, aB2, aB3);
          }
        }
        nvB = 4;
      }
    }
  }
  int myidxA, myidxB;
  {
    unsigned hi = (unsigned)(winA * (1.0 / 4096.0));
    double rem = winA - 4096.0 * (double)hi;
    myidxA = (NN - 1) - (int)rem;
    hi = (unsigned)(winB * (1.0 / 4096.0));
    rem = winB - 4096.0 * (double)hi;
    myidxB = (NN - 1) - (int)rem;
  }
  // ---- gather + max-pool, two points interleaved ----
  const float* Pb = ws + WS_P + (long long)b * NN * 128;
  float2 qA = ((const float2*)(ws + WS_Q + (long long)pt0 * 128))[lane];
  float2 qB = ((const float2*)(ws + WS_Q + (long long)(pt0 + 1) * 128))[lane];
  float mA0 = -3.4e38f, mA1 = -3.4e38f, mB0 = -3.4e38f, mB1 = -3.4e38f;
#pragma unroll
  for (int j = 0; j < KK; ++j) {
    int idA = __shfl(myidxA, j);
    int idB = __shfl(myidxB, j);
    float2 pA = ((const float2*)(Pb + (long long)idA * 128))[lane];
    float2 pB = ((const float2*)(Pb + (long long)idB * 128))[lane];
    mA0 = fmaxf(mA0, pA.x + qA.x);
    mA1 = fmaxf(mA1, pA.y + qA.y);
    mB0 = fmaxf(mB0, pB.x + qB.x);
    mB1 = fmaxf(mB1, pB.y + qB.y);
  }
  float2 feA = make_float2(fmaxf(mA0, 0.f), fmaxf(mA1, 0.f));
  float2 feB = make_float2(fmaxf(mB0, 0.f), fmaxf(mB1, 0.f));
  ((float2*)(ws + WS_FE + (long long)pt0 * 128))[lane] = feA;
  ((float2*)(ws + WS_FE + (long long)(pt0 + 1) * 128))[lane] = feB;
  ((float2*)(ldsFE + (w * 2) * 128))[lane] = feA;
  ((float2*)(ldsFE + (w * 2 + 1) * 128))[lane] = feB;
  __syncthreads();
  // ---- down-projections (k4 pattern): p = t>>5 in [0,8), oid = t&31 ----
  int p = t >> 5, oid = t & 31;
  float acc = 0.f;
#pragma unroll 8
  for (int c = 0; c < 128; ++c)
    acc = fmaf(ldsW[oid * 129 + c], ldsFE[p * 128 + c], acc);
  float v = fmaxf(acc, 0.f);
  int ptp = blockIdx.x * 8 + p;
  ws[WS_F12 + (long long)ptp * 32 + oid] = v;
  if (b == 0) {
    if (oid >= 16) {                          // f_space mean over f2's 16 channels
      float s = v;
#pragma unroll
      for (int d = 1; d < 16; d <<= 1) s += __shfl_xor(s, d);
      if (oid == 16) ws[WS_FS + (ptp & (NN - 1))] = s * 0.0625f;
    } else {
      atomicAdd(&ldsFC[oid], v);
    }
  }
  __syncthreads();
  if (b == 0 && t < 16) atomicAdd(ws + WS_FCACC + t, ldsFC[t]);
}

// ---------------- k5: outer-sqrt + up-proj + BN + Mish -> output --------------
__global__ __launch_bounds__(256) void k5_final(InPtrs in, float* ws,
                                                float* outf, __hip_bfloat16* outb) {
  __shared__ float fin[16 * 16];
  __shared__ float sWUP[2048];
  __shared__ float sSU[128], sCU[128];
  int flag = detect_bf16(in.p[0]);
  int t = threadIdx.x;
  int g = t >> 4;        // 0..15 : output group of 8
  int p = t & 15;        // point within tile
  int b = blockIdx.x >> 8;
  int n0 = (blockIdx.x & 255) << 4;
  int n = n0 + p;
  for (int i = t; i < 2048; i += 256) sWUP[i] = ldin(in.p[16], i, flag);
  if (t < 128) {
    float gu = ldin(in.p[18], t, flag), vu = ldin(in.p[21], t, flag);
    float su = gu / sqrtf(vu + 1e-5f);
    float bu = ldin(in.p[17], t, flag), beu = ldin(in.p[19], t, flag), mu = ldin(in.p[20], t, flag);
    sSU[t] = su; sCU[t] = su * (bu - mu) + beu;
  }
  {
    float fs = ws[WS_FS + n];
    float fc = ws[WS_FCACC + g] * (1.0f / NN);
    float f1v = ws[WS_F12 + (long long)(b * NN + n) * 32 + g];
    float f2v = ws[WS_F12 + (long long)(b * NN + n) * 32 + 16 + g];
    fin[p * 16 + g] = sqrtf(fc * fs + 1e-12f) + f1v + f2v;
  }
  __syncthreads();
  const float4* FE4 = (const float4*)(ws + WS_FE + (long long)(b * NN + n) * 128 + g * 8);
  float fev[8];
  {
    float4 a = FE4[0], c = FE4[1];
    fev[0] = a.x; fev[1] = a.y; fev[2] = a.z; fev[3] = a.w;
    fev[4] = c.x; fev[5] = c.y; fev[6] = c.z; fev[7] = c.w;
  }
#pragma unroll
  for (int j = 0; j < 8; ++j) {
    int o = g * 8 + j;
    float acc = 0.f;
#pragma unroll
    for (int c = 0; c < 16; ++c)
      acc = fmaf(sWUP[o * 16 + c], fin[p * 16 + c], acc);
    float fo = fmaf(sSU[o], acc, sCU[o]);
    fo = fmaxf(fo, 0.f);
    float fl = fev[j] - fo;
    // Mish(x) = x*(u^2+2u)/(u^2+2u+2), u=e^x; exact for x<=15, y=x beyond
    float u = __expf(fl);
    float nmr = u * (u + 2.f);
    float y = fl * __fdividef(nmr, nmr + 2.f);
    if (fl > 15.f) y = fl;
    long long oi = ((long long)b * CC + o) * NN + n;
    if (flag) outb[oi] = __float2bfloat16(y);
    else      outf[oi] = y;
  }
}

extern "C" void kernel_launch(void* const* d_in, const int* in_sizes, int n_in,
                              void* d_out, int out_size, void* d_ws, size_t ws_size,
                              hipStream_t stream) {
  (void)in_sizes; (void)out_size; (void)ws_size;
  float* ws = (float*)d_ws;
  InPtrs ip;
  for (int i = 0; i < 22; ++i) ip.p[i] = (i < n_in) ? d_in[i] : nullptr;
  hipLaunchKernelGGL(k1_pq,              dim3(256),          dim3(256), 0, stream, ip, ws);
  hipLaunchKernelGGL(k23_knn_fenc_down,  dim3(BB * NN / 8),  dim3(256), 0, stream, ip, ws);
  hipLaunchKernelGGL(k5_final,           dim3(BB * NN / 16), dim3(256), 0, stream, ip, ws,
                     (float*)d_out, (__hip_bfloat16*)d_out);
}

// Round 10
// 208.964 us; speedup vs baseline: 1.1308x; 1.1308x over previous
//
#include <hip/hip_runtime.h>
#include <hip/hip_bf16.h>

#define BB 2
#define CC 128
#define NN 4096
#define KK 20

// workspace offsets, in floats (total ~14.5 MB)
#define WS_FLAG   0
#define WS_FCACC  16
#define WS_S1     32
#define WS_C1     96
#define WS_S2     160
#define WS_C2     224
#define WS_SUP    288
#define WS_CUP    416
#define WS_FS     1024
#define WS_X      8192
#define WS_XX     32768
#define WS_W1     40960
#define WS_W2     41344
#define WS_WD1    57728
#define WS_WD2    59776
#define WS_WUP    61824
#define WS_P      65536
#define WS_Q      1114112
#define WS_FE     2326528
#define WS_F      WS_FE      /* F dead after k1; FE written in k23 */
#define WS_F12    3375104

struct InPtrs { const void* p[22]; };

__device__ __forceinline__ int detect_bf16(const void* xyz) {
  const unsigned* u = (const unsigned*)xyz;
  int cnt = 0;
  for (int i = 0; i < 64; ++i) {
    unsigned lo = u[i] & 0x7FFFu;
    cnt += (lo >= 0x3C00u && lo <= 0x4100u) ? 1 : 0;
  }
  return cnt >= 32;
}

__device__ __forceinline__ float ldin(const void* p, long long i, int flag) {
  if (flag) {
    unsigned short b = ((const unsigned short*)p)[i];
    return __uint_as_float(((unsigned)b) << 16);
  }
  return ((const float*)p)[i];
}

// order-preserving f32 -> u32 (exact): monotone for all finite floats
__device__ __forceinline__ unsigned sortable(float v) {
  unsigned u = __float_as_uint(v);
  return (u & 0x80000000u) ? ~u : (u | 0x80000000u);
}

// wave-wide max of u32 via DPP reduction chain; uniform result via readlane 63.
// Requires all 64 lanes active and uniform control flow.
__device__ __forceinline__ unsigned wave_max_u32(unsigned x) {
  unsigned t;
  t = (unsigned)__builtin_amdgcn_update_dpp(0, (int)x, 0x111, 0xF, 0xF, true); x = x > t ? x : t; // row_shr:1
  t = (unsigned)__builtin_amdgcn_update_dpp(0, (int)x, 0x112, 0xF, 0xF, true); x = x > t ? x : t; // row_shr:2
  t = (unsigned)__builtin_amdgcn_update_dpp(0, (int)x, 0x114, 0xF, 0xF, true); x = x > t ? x : t; // row_shr:4
  t = (unsigned)__builtin_amdgcn_update_dpp(0, (int)x, 0x118, 0xF, 0xF, true); x = x > t ? x : t; // row_shr:8
  t = (unsigned)__builtin_amdgcn_update_dpp(0, (int)x, 0x142, 0xF, 0xF, true); x = x > t ? x : t; // row_bcast:15
  t = (unsigned)__builtin_amdgcn_update_dpp(0, (int)x, 0x143, 0xF, 0xF, true); x = x > t ? x : t; // row_bcast:31
  return (unsigned)__builtin_amdgcn_readlane((int)x, 63);
}

// sorted-descending top-4 insert of (pd,idx); strict '>' keeps idx-ascending
// order among equal pds (stream feeds ascending idx) -> matches lax.top_k ties.
__device__ __forceinline__ void insert4p(unsigned pd, int idx,
    unsigned& p0, int& i0, unsigned& p1, int& i1,
    unsigned& p2, int& i2, unsigned& p3, int& i3) {
  bool b0 = pd > p0, b1 = pd > p1, b2 = pd > p2, b3 = pd > p3;
  p3 = b3 ? (b2 ? p2 : pd) : p3;  i3 = b3 ? (b2 ? i2 : idx) : i3;
  p2 = b2 ? (b1 ? p1 : pd) : p2;  i2 = b2 ? (b1 ? i1 : idx) : i2;
  p1 = b1 ? (b0 ? p0 : pd) : p1;  i1 = b1 ? (b0 ? i0 : idx) : i1;
  p0 = b0 ? pd : p0;              i0 = b0 ? idx : i0;
}

// ---------------- k0: dtype detect + convert inputs to f32 + fold BN params ----
__global__ __launch_bounds__(256) void k0_convert(InPtrs in, float* ws) {
  int flag = detect_bf16(in.p[0]);
  int gid = blockIdx.x * 256 + threadIdx.x;
  int stride = gridDim.x * 256;
  if (flag) {
    const ushort4* src = (const ushort4*)in.p[1];
    float4* dst = (float4*)(ws + WS_F);
    for (int i = gid; i < 262144; i += stride) {
      ushort4 s = src[i];
      dst[i] = make_float4(
        __uint_as_float(((unsigned)s.x) << 16), __uint_as_float(((unsigned)s.y) << 16),
        __uint_as_float(((unsigned)s.z) << 16), __uint_as_float(((unsigned)s.w) << 16));
    }
  } else {
    const float4* src = (const float4*)in.p[1];
    float4* dst = (float4*)(ws + WS_F);
    for (int i = gid; i < 262144; i += stride) dst[i] = src[i];
  }
  const int T0 = 24576;           // xyz end
  const int T1 = T0 + 384;        // w_mlp1 end   (24960)
  const int T2 = T1 + 16384;      // w_mlp2 end   (41344)
  const int T3 = T2 + 2048;       // w_down1 end  (43392)
  const int T4 = T3 + 2048;       // w_down2 end  (45440)
  const int T5 = T4 + 2048;       // w_up end     (47488)
  for (int i = gid; i < T5; i += stride) {
    const void* src; int off, dst;
    if      (i < T0) { src = in.p[0];  off = i;      dst = WS_X   + off; }
    else if (i < T1) { src = in.p[2];  off = i - T0; dst = WS_W1  + off; }
    else if (i < T2) { src = in.p[8];  off = i - T1; dst = WS_W2  + off; }
    else if (i < T3) { src = in.p[14]; off = i - T2; dst = WS_WD1 + off; }
    else if (i < T4) { src = in.p[15]; off = i - T3; dst = WS_WD2 + off; }
    else             { src = in.p[16]; off = i - T4; dst = WS_WUP + off; }
    ws[dst] = ldin(src, off, flag);
  }
  if (blockIdx.x == 0) {
    int t = threadIdx.x;
    if (t < 64) {
      float b1 = ldin(in.p[3], t, flag), g1 = ldin(in.p[4], t, flag);
      float be1 = ldin(in.p[5], t, flag), m1 = ldin(in.p[6], t, flag), v1 = ldin(in.p[7], t, flag);
      float s1 = g1 / sqrtf(v1 + 1e-5f);
      ws[WS_S1 + t] = s1;
      ws[WS_C1 + t] = s1 * (b1 - m1) + be1;
      float b2 = ldin(in.p[9], t, flag), g2 = ldin(in.p[10], t, flag);
      float be2 = ldin(in.p[11], t, flag), m2 = ldin(in.p[12], t, flag), v2 = ldin(in.p[13], t, flag);
      float s2 = g2 / sqrtf(v2 + 1e-5f);
      ws[WS_S2 + t] = s2;
      ws[WS_C2 + t] = s2 * (b2 - m2) + be2;
    }
    if (t < 128) {
      float bu = ldin(in.p[17], t, flag), gu = ldin(in.p[18], t, flag);
      float beu = ldin(in.p[19], t, flag), mu = ldin(in.p[20], t, flag), vu = ldin(in.p[21], t, flag);
      float su = gu / sqrtf(vu + 1e-5f);
      ws[WS_SUP + t] = su;
      ws[WS_CUP + t] = su * (bu - mu) + beu;
    }
    if (t < 16) ws[WS_FCACC + t] = 0.f;
    if (t == 0) ((int*)ws)[WS_FLAG] = flag;
  }
}

// ---------------- k1: P,Q projections — W2 staged in LDS, 256 blocks ----------
__global__ __launch_bounds__(256) void k1_pq(float* ws) {
  __shared__ float ldsW[64 * 128];   // [o][c-half 64 for P | 64 for Q] 32KB
  __shared__ float ldsF[64 * 32];    // [c-half][m] 8KB
  int t = threadIdx.x;
  int bid = blockIdx.x;              // 256 blocks
  int b = bid >> 7;
  int m0 = (bid & 127) << 5;
  int w = t >> 6, sub = (t >> 5) & 1, mloc = t & 31;
  const float* F = ws + WS_F + (long long)b * CC * NN;
  const float* W2 = ws + WS_W2;
  float accP[8], accQ[8];
#pragma unroll
  for (int j = 0; j < 8; ++j) { accP[j] = 0.f; accQ[j] = 0.f; }
  for (int half = 0; half < 2; ++half) {
    if (half) __syncthreads();
    for (int i = t; i < 64 * 128; i += 256) {
      int o = i >> 7, r = i & 127;
      int c = (r & 63) + half * 64 + ((r >> 6) << 7);   // +128 for Q part
      ldsW[i] = W2[o * 256 + c];
    }
    for (int i = t; i < 64 * 32; i += 256) {
      int cl = i >> 5, ml = i & 31;
      ldsF[i] = F[(long long)(half * 64 + cl) * NN + m0 + ml];
    }
    __syncthreads();
    for (int cl = 0; cl < 64; ++cl) {
      float f = ldsF[cl * 32 + mloc];
#pragma unroll
      for (int j = 0; j < 8; ++j) {
        int o = w * 16 + sub * 8 + j;
        accP[j] = fmaf(ldsW[o * 128 + cl], f, accP[j]);
        accQ[j] = fmaf(ldsW[o * 128 + 64 + cl], f, accQ[j]);
      }
    }
  }
  int m = m0 + mloc;
  const float* X = ws + WS_X + (long long)b * 3 * NN;
  float x0 = X[m], x1 = X[NN + m], x2 = X[2 * NN + m];
  const float* W1 = ws + WS_W1;
  float* P = ws + WS_P + ((long long)(b * NN + m)) * 128;
  float* Q = ws + WS_Q + ((long long)(b * NN + m)) * 128;
#pragma unroll
  for (int j = 0; j < 8; ++j) {
    int o = w * 16 + sub * 8 + j;
    float s1 = ws[WS_S1 + o], c1 = ws[WS_C1 + o];
    float px = fmaf(W1[o * 6 + 2], x2, fmaf(W1[o * 6 + 1], x1, W1[o * 6 + 0] * x0));
    float qx = fmaf(W1[o * 6 + 5], x2, fmaf(W1[o * 6 + 4], x1, W1[o * 6 + 3] * x0));
    P[o] = s1 * px;
    Q[o] = fmaf(s1, qx - px, c1);
    float s2 = ws[WS_S2 + o], c2 = ws[WS_C2 + o];
    P[64 + o] = s2 * accP[j];
    Q[64 + o] = fmaf(s2, accQ[j] - accP[j], c2);
  }
  if (t < 32) {
    float xx = __fadd_rn(__fadd_rn(__fmul_rn(x0, x0), __fmul_rn(x1, x1)), __fmul_rn(x2, x2));
    ws[WS_XX + b * NN + m] = xx;
  }
}

// ------- k23: KNN top-20 (u32 keys + DPP wave-max) + gather + max-pool --------
__global__ __launch_bounds__(256) void k23_knn_fenc(float* ws) {
  int t = threadIdx.x;
  int w = t >> 6, lane = t & 63;
  int pt = blockIdx.x * 4 + w;                // 2048 blocks, 1 wave = 1 point
  int b = pt >> 12;
  int n = pt & (NN - 1);
  const float* X = ws + WS_X + (long long)b * 3 * NN;
  const float* XX = ws + WS_XX + (long long)b * NN;
  float xc0 = X[n], xc1 = X[NN + n], xc2 = X[2 * NN + n], xxn = XX[n];
  unsigned p0 = 0, p1 = 0, p2 = 0, p3 = 0;
  int i0 = 0, i1 = 0, i2 = 0, i3 = 0;
#pragma unroll 4
  for (int s = 0; s < 64; ++s) {
    int m = s * 64 + lane;
    float c0 = X[m], c1 = X[NN + m], c2 = X[2 * NN + m], xxm = XX[m];
    float inner = __fadd_rn(__fadd_rn(__fmul_rn(c0, xc0), __fmul_rn(c1, xc1)), __fmul_rn(c2, xc2));
    float pd = __fsub_rn(__fsub_rn(__fmul_rn(2.0f, inner), xxn), xxm);
    insert4p(sortable(pd), m, p0, i0, p1, i1, p2, i2, p3, i3);
  }
  unsigned long long used = 0;
  int nv = 4;
  int winner = 0;                             // lane r keeps round-r winner index
  for (int r = 0; r < KK; ++r) {
    unsigned spd = wave_max_u32(p0);          // max pd among heads (uniform)
    unsigned cand = (p0 == spd) ? (unsigned)(4095 - i0) : 0u;
    unsigned sidx = 4095u - wave_max_u32(cand); // min idx among ties (uniform)
    if (lane == r) winner = (int)sidx;
    if (p0 == spd && i0 == (int)sidx) {       // unique owner lane
      used |= 1ull << (i0 >> 6);
      p0 = p1; i0 = i1; p1 = p2; i1 = i2; p2 = p3; i2 = i3; p3 = 0; i3 = 0;
      if (--nv == 0) {                        // rare: lane supplied >=5 winners
        p0 = p1 = p2 = p3 = 0; i0 = i1 = i2 = i3 = 0;
#pragma unroll 1
        for (int s = 0; s < 64; ++s) {
          if (!((used >> s) & 1ull)) {
            int m = s * 64 + lane;
            float c0 = X[m], c1 = X[NN + m], c2 = X[2 * NN + m], xxm = XX[m];
            float inner = __fadd_rn(__fadd_rn(__fmul_rn(c0, xc0), __fmul_rn(c1, xc1)), __fmul_rn(c2, xc2));
            float pd = __fsub_rn(__fsub_rn(__fmul_rn(2.0f, inner), xxn), xxm);
            insert4p(sortable(pd), m, p0, i0, p1, i1, p2, i2, p3, i3);
          }
        }
        nv = 4;
      }
    }
  }
  // gather + max-pool
  const float* Q = ws + WS_Q + (long long)pt * 128;
  const float* Pb = ws + WS_P + (long long)b * NN * 128;
  float2 q = ((const float2*)Q)[lane];
  float mx0 = -3.4e38f, mx1 = -3.4e38f;
#pragma unroll
  for (int j = 0; j < KK; ++j) {
    int id = __shfl(winner, j);
    float2 p = ((const float2*)(Pb + (long long)id * 128))[lane];
    mx0 = fmaxf(mx0, p.x + q.x);
    mx1 = fmaxf(mx1, p.y + q.y);
  }
  float2 fe = make_float2(fmaxf(mx0, 0.f), fmaxf(mx1, 0.f));
  ((float2*)(ws + WS_FE + (long long)pt * 128))[lane] = fe;
}

// ---------------- k4: down-projections f1,f2 + f_space + f_channel accum ------
__global__ __launch_bounds__(256) void k4_down(float* ws) {
  __shared__ float ldsFE[8 * 128];
  __shared__ float ldsW[32 * 129];
  __shared__ float ldsFC[16];
  int t = threadIdx.x;
  int b = blockIdx.x >> 9;
  int n0 = (blockIdx.x & 511) << 3;
  for (int i = t; i < 8 * 128; i += 256) {
    int p = i >> 7, c = i & 127;
    ldsFE[i] = ws[WS_FE + (long long)(b * NN + n0 + p) * 128 + c];
  }
  for (int i = t; i < 32 * 128; i += 256) {
    int o = i >> 7, c = i & 127;
    ldsW[o * 129 + c] = (o < 16) ? ws[WS_WD1 + o * 128 + c] : ws[WS_WD2 + (o - 16) * 128 + c];
  }
  if (t < 16) ldsFC[t] = 0.f;
  __syncthreads();
  int p = t >> 5, oid = t & 31;
  float acc = 0.f;
#pragma unroll 8
  for (int c = 0; c < 128; ++c)
    acc = fmaf(ldsW[oid * 129 + c], ldsFE[p * 128 + c], acc);
  float v = fmaxf(acc, 0.f);
  ws[WS_F12 + (long long)(b * NN + n0 + p) * 32 + oid] = v;
  if (b == 0) {
    if (oid >= 16) {
      float s = v;
#pragma unroll
      for (int d = 1; d < 16; d <<= 1) s += __shfl_xor(s, d);
      if (oid == 16) ws[WS_FS + n0 + p] = s * 0.0625f;
    } else {
      atomicAdd(&ldsFC[oid], v);
    }
  }
  __syncthreads();
  if (b == 0 && t < 16) atomicAdd(ws + WS_FCACC + t, ldsFC[t]);
}

// ---------------- k5: outer-sqrt + up-proj + BN + Mish -> output --------------
__global__ __launch_bounds__(256) void k5_final(float* ws, float* outf, __hip_bfloat16* outb) {
  __shared__ float fin[16 * 16];
  int t = threadIdx.x;
  int g = t >> 4;        // 0..15 : output group of 8
  int p = t & 15;        // point within tile
  int b = blockIdx.x >> 8;
  int n0 = (blockIdx.x & 255) << 4;
  int n = n0 + p;
  int flag = ((const int*)ws)[WS_FLAG];
  {
    float fs = ws[WS_FS + n];
    float fc = ws[WS_FCACC + g] * (1.0f / NN);
    float f1v = ws[WS_F12 + (long long)(b * NN + n) * 32 + g];
    float f2v = ws[WS_F12 + (long long)(b * NN + n) * 32 + 16 + g];
    fin[p * 16 + g] = sqrtf(fc * fs + 1e-12f) + f1v + f2v;
  }
  __syncthreads();
  const float4* FE4 = (const float4*)(ws + WS_FE + (long long)(b * NN + n) * 128 + g * 8);
  float fev[8];
  {
    float4 a = FE4[0], c = FE4[1];
    fev[0] = a.x; fev[1] = a.y; fev[2] = a.z; fev[3] = a.w;
    fev[4] = c.x; fev[5] = c.y; fev[6] = c.z; fev[7] = c.w;
  }
#pragma unroll
  for (int j = 0; j < 8; ++j) {
    int o = g * 8 + j;
    float acc = 0.f;
#pragma unroll
    for (int c = 0; c < 16; ++c)
      acc = fmaf(ws[WS_WUP + o * 16 + c], fin[p * 16 + c], acc);
    float fo = fmaf(ws[WS_SUP + o], acc, ws[WS_CUP + o]);
    fo = fmaxf(fo, 0.f);
    float fl = fev[j] - fo;
    // Mish(x) = x*(u^2+2u)/(u^2+2u+2), u=e^x; exact for x<=15, y=x beyond
    float u = __expf(fl);
    float nmr = u * (u + 2.f);
    float y = fl * __fdividef(nmr, nmr + 2.f);
    if (fl > 15.f) y = fl;
    long long oi = ((long long)b * CC + o) * NN + n;
    if (flag) outb[oi] = __float2bfloat16(y);
    else      outf[oi] = y;
  }
}

extern "C" void kernel_launch(void* const* d_in, const int* in_sizes, int n_in,
                              void* d_out, int out_size, void* d_ws, size_t ws_size,
                              hipStream_t stream) {
  (void)in_sizes; (void)out_size; (void)ws_size;
  float* ws = (float*)d_ws;
  InPtrs ip;
  for (int i = 0; i < 22; ++i) ip.p[i] = (i < n_in) ? d_in[i] : nullptr;
  hipLaunchKernelGGL(k0_convert,   dim3(512),          dim3(256), 0, stream, ip, ws);
  hipLaunchKernelGGL(k1_pq,        dim3(256),          dim3(256), 0, stream, ws);
  hipLaunchKernelGGL(k23_knn_fenc, dim3(BB * NN / 4),  dim3(256), 0, stream, ws);
  hipLaunchKernelGGL(k4_down,      dim3(BB * NN / 8),  dim3(256), 0, stream, ws);
  hipLaunchKernelGGL(k5_final,     dim3(BB * NN / 16), dim3(256), 0, stream, ws,
                     (float*)d_out, (__hip_bfloat16*)d_out);
}

// Round 11
// 203.786 us; speedup vs baseline: 1.1596x; 1.0254x over previous
//
#include <hip/hip_runtime.h>
#include <hip/hip_bf16.h>

#define BB 2
#define CC 128
#define NN 4096
#define KK 20

// workspace offsets, in floats (total ~14.5 MB)
#define WS_FLAG   0
#define WS_FCACC  16
#define WS_S1     32
#define WS_C1     96
#define WS_S2     160
#define WS_C2     224
#define WS_SUP    288
#define WS_CUP    416
#define WS_FS     1024
#define WS_X      8192
#define WS_XX     32768
#define WS_W1     40960
#define WS_W2T    41344      /* W2 transposed: [c<256][o<64] */
#define WS_WD1    57728
#define WS_WD2    59776
#define WS_WUP    61824
#define WS_P      65536
#define WS_Q      1114112
#define WS_FE     2326528
#define WS_F      WS_FE      /* F dead after k1; FE written in k23 */
#define WS_F12    3375104

struct InPtrs { const void* p[22]; };

__device__ __forceinline__ int detect_bf16(const void* xyz) {
  const unsigned* u = (const unsigned*)xyz;
  int cnt = 0;
  for (int i = 0; i < 64; ++i) {
    unsigned lo = u[i] & 0x7FFFu;
    cnt += (lo >= 0x3C00u && lo <= 0x4100u) ? 1 : 0;
  }
  return cnt >= 32;
}

__device__ __forceinline__ float ldin(const void* p, long long i, int flag) {
  if (flag) {
    unsigned short b = ((const unsigned short*)p)[i];
    return __uint_as_float(((unsigned)b) << 16);
  }
  return ((const float*)p)[i];
}

// order-preserving f32 -> u32 (exact): monotone for all finite floats
__device__ __forceinline__ unsigned sortable(float v) {
  unsigned u = __float_as_uint(v);
  return (u & 0x80000000u) ? ~u : (u | 0x80000000u);
}

// wave-wide max of u32 via DPP reduction chain; uniform result via readlane 63.
__device__ __forceinline__ unsigned wave_max_u32(unsigned x) {
  unsigned t;
  t = (unsigned)__builtin_amdgcn_update_dpp(0, (int)x, 0x111, 0xF, 0xF, true); x = x > t ? x : t; // row_shr:1
  t = (unsigned)__builtin_amdgcn_update_dpp(0, (int)x, 0x112, 0xF, 0xF, true); x = x > t ? x : t; // row_shr:2
  t = (unsigned)__builtin_amdgcn_update_dpp(0, (int)x, 0x114, 0xF, 0xF, true); x = x > t ? x : t; // row_shr:4
  t = (unsigned)__builtin_amdgcn_update_dpp(0, (int)x, 0x118, 0xF, 0xF, true); x = x > t ? x : t; // row_shr:8
  t = (unsigned)__builtin_amdgcn_update_dpp(0, (int)x, 0x142, 0xF, 0xF, true); x = x > t ? x : t; // row_bcast:15
  t = (unsigned)__builtin_amdgcn_update_dpp(0, (int)x, 0x143, 0xF, 0xF, true); x = x > t ? x : t; // row_bcast:31
  return (unsigned)__builtin_amdgcn_readlane((int)x, 63);
}

// sorted-descending top-4 insert of (pd,idx); strict '>' keeps idx-ascending
// order among equal pds (stream feeds ascending idx) -> matches lax.top_k ties.
__device__ __forceinline__ void insert4p(unsigned pd, int idx,
    unsigned& p0, int& i0, unsigned& p1, int& i1,
    unsigned& p2, int& i2, unsigned& p3, int& i3) {
  bool b0 = pd > p0, b1 = pd > p1, b2 = pd > p2, b3 = pd > p3;
  p3 = b3 ? (b2 ? p2 : pd) : p3;  i3 = b3 ? (b2 ? i2 : idx) : i3;
  p2 = b2 ? (b1 ? p1 : pd) : p2;  i2 = b2 ? (b1 ? i1 : idx) : i2;
  p1 = b1 ? (b0 ? p0 : pd) : p1;  i1 = b1 ? (b0 ? i0 : idx) : i1;
  p0 = b0 ? pd : p0;              i0 = b0 ? idx : i0;
}

// ---------------- k0: dtype detect + convert inputs to f32 + fold BN params ----
__global__ __launch_bounds__(256) void k0_convert(InPtrs in, float* ws) {
  int flag = detect_bf16(in.p[0]);
  int gid = blockIdx.x * 256 + threadIdx.x;
  int stride = gridDim.x * 256;
  if (flag) {
    const ushort4* src = (const ushort4*)in.p[1];
    float4* dst = (float4*)(ws + WS_F);
    for (int i = gid; i < 262144; i += stride) {
      ushort4 s = src[i];
      dst[i] = make_float4(
        __uint_as_float(((unsigned)s.x) << 16), __uint_as_float(((unsigned)s.y) << 16),
        __uint_as_float(((unsigned)s.z) << 16), __uint_as_float(((unsigned)s.w) << 16));
    }
  } else {
    const float4* src = (const float4*)in.p[1];
    float4* dst = (float4*)(ws + WS_F);
    for (int i = gid; i < 262144; i += stride) dst[i] = src[i];
  }
  // W2 transpose: W2T[c][o] = W2[o][c]
  for (int i = gid; i < 16384; i += stride) {
    int c = i >> 6, o = i & 63;
    ws[WS_W2T + i] = ldin(in.p[8], o * 256 + c, flag);
  }
  // xyz + small weight matrices
  const int T0 = 24576;           // xyz end
  const int T1 = T0 + 384;        // w_mlp1 end
  const int T2 = T1 + 2048;       // w_down1 end
  const int T3 = T2 + 2048;       // w_down2 end
  const int T4 = T3 + 2048;       // w_up end (31104)
  for (int i = gid; i < T4; i += stride) {
    const void* src; int off, dst;
    if      (i < T0) { src = in.p[0];  off = i;      dst = WS_X   + off; }
    else if (i < T1) { src = in.p[2];  off = i - T0; dst = WS_W1  + off; }
    else if (i < T2) { src = in.p[14]; off = i - T1; dst = WS_WD1 + off; }
    else if (i < T3) { src = in.p[15]; off = i - T2; dst = WS_WD2 + off; }
    else             { src = in.p[16]; off = i - T3; dst = WS_WUP + off; }
    ws[dst] = ldin(src, off, flag);
  }
  if (blockIdx.x == 0) {
    int t = threadIdx.x;
    if (t < 64) {
      float b1 = ldin(in.p[3], t, flag), g1 = ldin(in.p[4], t, flag);
      float be1 = ldin(in.p[5], t, flag), m1 = ldin(in.p[6], t, flag), v1 = ldin(in.p[7], t, flag);
      float s1 = g1 / sqrtf(v1 + 1e-5f);
      ws[WS_S1 + t] = s1;
      ws[WS_C1 + t] = s1 * (b1 - m1) + be1;
      float b2 = ldin(in.p[9], t, flag), g2 = ldin(in.p[10], t, flag);
      float be2 = ldin(in.p[11], t, flag), m2 = ldin(in.p[12], t, flag), v2 = ldin(in.p[13], t, flag);
      float s2 = g2 / sqrtf(v2 + 1e-5f);
      ws[WS_S2 + t] = s2;
      ws[WS_C2 + t] = s2 * (b2 - m2) + be2;
    }
    if (t < 128) {
      float bu = ldin(in.p[17], t, flag), gu = ldin(in.p[18], t, flag);
      float beu = ldin(in.p[19], t, flag), mu = ldin(in.p[20], t, flag), vu = ldin(in.p[21], t, flag);
      float su = gu / sqrtf(vu + 1e-5f);
      ws[WS_SUP + t] = su;
      ws[WS_CUP + t] = su * (bu - mu) + beu;
    }
    if (t < 16) ws[WS_FCACC + t] = 0.f;
    if (t == 0) ((int*)ws)[WS_FLAG] = flag;
  }
}

// ---------------- k1: P,Q projections — no LDS, scalar W2T loads --------------
// 512 blocks; wave = 64 m-points x 4 o-channels (o uniform per wave -> s_load).
__global__ __launch_bounds__(256) void k1_pq(float* ws) {
  int t = threadIdx.x;
  int bid = blockIdx.x;              // 512 = 2b x 64mt x 4ot
  int b = bid >> 8;
  int mt = (bid >> 2) & 63;
  int ot = bid & 3;
  int w = __builtin_amdgcn_readfirstlane(t >> 6);
  int lane = t & 63;
  int o0 = ot * 16 + w * 4;          // wave-uniform
  int m = (mt << 6) + lane;
  const float* F = ws + WS_F + (long long)b * CC * NN;
  const float* W2T = ws + WS_W2T;
  float accP[4] = {0.f, 0.f, 0.f, 0.f}, accQ[4] = {0.f, 0.f, 0.f, 0.f};
#pragma unroll 4
  for (int c = 0; c < 128; ++c) {
    float f = F[c * NN + m];
#pragma unroll
    for (int j = 0; j < 4; ++j) {
      accP[j] = fmaf(W2T[c * 64 + o0 + j], f, accP[j]);
      accQ[j] = fmaf(W2T[(128 + c) * 64 + o0 + j], f, accQ[j]);
    }
  }
  const float* X = ws + WS_X + (long long)b * 3 * NN;
  float x0 = X[m], x1 = X[NN + m], x2 = X[2 * NN + m];
  const float* W1 = ws + WS_W1;
  float* P = ws + WS_P + ((long long)(b * NN + m)) * 128;
  float* Q = ws + WS_Q + ((long long)(b * NN + m)) * 128;
  float4 p1v, q1v, p2v, q2v;
#pragma unroll
  for (int j = 0; j < 4; ++j) {
    int o = o0 + j;
    float s1 = ws[WS_S1 + o], c1 = ws[WS_C1 + o];
    float px = fmaf(W1[o * 6 + 2], x2, fmaf(W1[o * 6 + 1], x1, W1[o * 6 + 0] * x0));
    float qx = fmaf(W1[o * 6 + 5], x2, fmaf(W1[o * 6 + 4], x1, W1[o * 6 + 3] * x0));
    (&p1v.x)[j] = s1 * px;
    (&q1v.x)[j] = fmaf(s1, qx - px, c1);
    float s2 = ws[WS_S2 + o], c2 = ws[WS_C2 + o];
    (&p2v.x)[j] = s2 * accP[j];
    (&q2v.x)[j] = fmaf(s2, accQ[j] - accP[j], c2);
  }
  *(float4*)(P + o0)      = p1v;
  *(float4*)(P + 64 + o0) = p2v;
  *(float4*)(Q + o0)      = q1v;
  *(float4*)(Q + 64 + o0) = q2v;
  if (ot == 0 && w == 0) {
    float xx = __fadd_rn(__fadd_rn(__fmul_rn(x0, x0), __fmul_rn(x1, x1)), __fmul_rn(x2, x2));
    ws[WS_XX + b * NN + m] = xx;
  }
}

// ------- k23: KNN top-20 (u32 keys + DPP wave-max) + gather + max-pool --------
__global__ __launch_bounds__(256) void k23_knn_fenc(float* ws) {
  int t = threadIdx.x;
  int w = t >> 6, lane = t & 63;
  int pt = blockIdx.x * 4 + w;                // 2048 blocks, 1 wave = 1 point
  int b = pt >> 12;
  int n = pt & (NN - 1);
  const float* X = ws + WS_X + (long long)b * 3 * NN;
  const float* XX = ws + WS_XX + (long long)b * NN;
  float xc0 = X[n], xc1 = X[NN + n], xc2 = X[2 * NN + n], xxn = XX[n];
  unsigned p0 = 0, p1 = 0, p2 = 0, p3 = 0;
  int i0 = 0, i1 = 0, i2 = 0, i3 = 0;
#pragma unroll 4
  for (int s = 0; s < 64; ++s) {
    int m = s * 64 + lane;
    float c0 = X[m], c1 = X[NN + m], c2 = X[2 * NN + m], xxm = XX[m];
    float inner = __fadd_rn(__fadd_rn(__fmul_rn(c0, xc0), __fmul_rn(c1, xc1)), __fmul_rn(c2, xc2));
    float pd = __fsub_rn(__fsub_rn(__fmul_rn(2.0f, inner), xxn), xxm);
    insert4p(sortable(pd), m, p0, i0, p1, i1, p2, i2, p3, i3);
  }
  unsigned long long used = 0;
  int nv = 4;
  int winner = 0;                             // lane r keeps round-r winner index
  for (int r = 0; r < KK; ++r) {
    unsigned spd = wave_max_u32(p0);          // max pd among heads (uniform)
    unsigned cand = (p0 == spd) ? (unsigned)(4095 - i0) : 0u;
    unsigned sidx = 4095u - wave_max_u32(cand); // min idx among ties (uniform)
    if (lane == r) winner = (int)sidx;
    if (p0 == spd && i0 == (int)sidx) {       // unique owner lane
      used |= 1ull << (i0 >> 6);
      p0 = p1; i0 = i1; p1 = p2; i1 = i2; p2 = p3; i2 = i3; p3 = 0; i3 = 0;
      if (--nv == 0) {                        // rare: lane supplied >=5 winners
        p0 = p1 = p2 = p3 = 0; i0 = i1 = i2 = i3 = 0;
#pragma unroll 1
        for (int s = 0; s < 64; ++s) {
          if (!((used >> s) & 1ull)) {
            int m = s * 64 + lane;
            float c0 = X[m], c1 = X[NN + m], c2 = X[2 * NN + m], xxm = XX[m];
            float inner = __fadd_rn(__fadd_rn(__fmul_rn(c0, xc0), __fmul_rn(c1, xc1)), __fmul_rn(c2, xc2));
            float pd = __fsub_rn(__fsub_rn(__fmul_rn(2.0f, inner), xxn), xxm);
            insert4p(sortable(pd), m, p0, i0, p1, i1, p2, i2, p3, i3);
          }
        }
        nv = 4;
      }
    }
  }
  // gather + max-pool
  const float* Q = ws + WS_Q + (long long)pt * 128;
  const float* Pb = ws + WS_P + (long long)b * NN * 128;
  float2 q = ((const float2*)Q)[lane];
  float mx0 = -3.4e38f, mx1 = -3.4e38f;
#pragma unroll
  for (int j = 0; j < KK; ++j) {
    int id = __shfl(winner, j);
    float2 p = ((const float2*)(Pb + (long long)id * 128))[lane];
    mx0 = fmaxf(mx0, p.x + q.x);
    mx1 = fmaxf(mx1, p.y + q.y);
  }
  float2 fe = make_float2(fmaxf(mx0, 0.f), fmaxf(mx1, 0.f));
  ((float2*)(ws + WS_FE + (long long)pt * 128))[lane] = fe;
}

// ---------------- k4: down-projections f1,f2 + f_space + f_channel accum ------
__global__ __launch_bounds__(256) void k4_down(float* ws) {
  __shared__ float ldsFE[8 * 128];
  __shared__ float ldsW[32 * 129];
  __shared__ float ldsFC[16];
  int t = threadIdx.x;
  int b = blockIdx.x >> 9;
  int n0 = (blockIdx.x & 511) << 3;
  for (int i = t; i < 8 * 128; i += 256) {
    int p = i >> 7, c = i & 127;
    ldsFE[i] = ws[WS_FE + (long long)(b * NN + n0 + p) * 128 + c];
  }
  for (int i = t; i < 32 * 128; i += 256) {
    int o = i >> 7, c = i & 127;
    ldsW[o * 129 + c] = (o < 16) ? ws[WS_WD1 + o * 128 + c] : ws[WS_WD2 + (o - 16) * 128 + c];
  }
  if (t < 16) ldsFC[t] = 0.f;
  __syncthreads();
  int p = t >> 5, oid = t & 31;
  float acc = 0.f;
#pragma unroll 8
  for (int c = 0; c < 128; ++c)
    acc = fmaf(ldsW[oid * 129 + c], ldsFE[p * 128 + c], acc);
  float v = fmaxf(acc, 0.f);
  ws[WS_F12 + (long long)(b * NN + n0 + p) * 32 + oid] = v;
  if (b == 0) {
    if (oid >= 16) {
      float s = v;
#pragma unroll
      for (int d = 1; d < 16; d <<= 1) s += __shfl_xor(s, d);
      if (oid == 16) ws[WS_FS + n0 + p] = s * 0.0625f;
    } else {
      atomicAdd(&ldsFC[oid], v);
    }
  }
  __syncthreads();
  if (b == 0 && t < 16) atomicAdd(ws + WS_FCACC + t, ldsFC[t]);
}

// ---------------- k5: outer-sqrt + up-proj + BN + Mish -> output --------------
__global__ __launch_bounds__(256) void k5_final(float* ws, float* outf, __hip_bfloat16* outb) {
  __shared__ float fin[16 * 16];
  int t = threadIdx.x;
  int g = t >> 4;        // 0..15 : output group of 8
  int p = t & 15;        // point within tile
  int b = blockIdx.x >> 8;
  int n0 = (blockIdx.x & 255) << 4;
  int n = n0 + p;
  int flag = ((const int*)ws)[WS_FLAG];
  {
    float fs = ws[WS_FS + n];
    float fc = ws[WS_FCACC + g] * (1.0f / NN);
    float f1v = ws[WS_F12 + (long long)(b * NN + n) * 32 + g];
    float f2v = ws[WS_F12 + (long long)(b * NN + n) * 32 + 16 + g];
    fin[p * 16 + g] = sqrtf(fc * fs + 1e-12f) + f1v + f2v;
  }
  __syncthreads();
  const float4* FE4 = (const float4*)(ws + WS_FE + (long long)(b * NN + n) * 128 + g * 8);
  float fev[8];
  {
    float4 a = FE4[0], c = FE4[1];
    fev[0] = a.x; fev[1] = a.y; fev[2] = a.z; fev[3] = a.w;
    fev[4] = c.x; fev[5] = c.y; fev[6] = c.z; fev[7] = c.w;
  }
#pragma unroll
  for (int j = 0; j < 8; ++j) {
    int o = g * 8 + j;
    float acc = 0.f;
#pragma unroll
    for (int c = 0; c < 16; ++c)
      acc = fmaf(ws[WS_WUP + o * 16 + c], fin[p * 16 + c], acc);
    float fo = fmaf(ws[WS_SUP + o], acc, ws[WS_CUP + o]);
    fo = fmaxf(fo, 0.f);
    float fl = fev[j] - fo;
    // Mish(x) = x*(u^2+2u)/(u^2+2u+2), u=e^x; exact for x<=15, y=x beyond
    float u = __expf(fl);
    float nmr = u * (u + 2.f);
    float y = fl * __fdividef(nmr, nmr + 2.f);
    if (fl > 15.f) y = fl;
    long long oi = ((long long)b * CC + o) * NN + n;
    if (flag) outb[oi] = __float2bfloat16(y);
    else      outf[oi] = y;
  }
}

extern "C" void kernel_launch(void* const* d_in, const int* in_sizes, int n_in,
                              void* d_out, int out_size, void* d_ws, size_t ws_size,
                              hipStream_t stream) {
  (void)in_sizes; (void)out_size; (void)ws_size;
  float* ws = (float*)d_ws;
  InPtrs ip;
  for (int i = 0; i < 22; ++i) ip.p[i] = (i < n_in) ? d_in[i] : nullptr;
  hipLaunchKernelGGL(k0_convert,   dim3(512),          dim3(256), 0, stream, ip, ws);
  hipLaunchKernelGGL(k1_pq,        dim3(512),          dim3(256), 0, stream, ws);
  hipLaunchKernelGGL(k23_knn_fenc, dim3(BB * NN / 4),  dim3(256), 0, stream, ws);
  hipLaunchKernelGGL(k4_down,      dim3(BB * NN / 8),  dim3(256), 0, stream, ws);
  hipLaunchKernelGGL(k5_final,     dim3(BB * NN / 16), dim3(256), 0, stream, ws,
                     (float*)d_out, (__hip_bfloat16*)d_out);
}

// Round 14
// 199.045 us; speedup vs baseline: 1.1872x; 1.0238x over previous
//
#include <hip/hip_runtime.h>
#include <hip/hip_bf16.h>

#define BB 2
#define CC 128
#define NN 4096
#define KK 20

// workspace offsets, in floats (total ~14.5 MB)
#define WS_FLAG   0
#define WS_FCACC  16
#define WS_S1     32
#define WS_C1     96
#define WS_S2     160
#define WS_C2     224
#define WS_SUP    288
#define WS_CUP    416
#define WS_FS     1024
#define WS_X      8192
#define WS_XX     32768
#define WS_W1     40960
#define WS_W2T    41344      /* W2 transposed: [c<256][o<64] */
#define WS_WD1    57728
#define WS_WD2    59776
#define WS_WUP    61824
#define WS_P      65536
#define WS_Q      1114112
#define WS_FE     2326528
#define WS_F      WS_FE      /* F dead after k1; FE written in k23 */
#define WS_F12    3375104

struct InPtrs { const void* p[22]; };

__device__ __forceinline__ int detect_bf16(const void* xyz) {
  const unsigned* u = (const unsigned*)xyz;
  int cnt = 0;
  for (int i = 0; i < 64; ++i) {
    unsigned lo = u[i] & 0x7FFFu;
    cnt += (lo >= 0x3C00u && lo <= 0x4100u) ? 1 : 0;
  }
  return cnt >= 32;
}

__device__ __forceinline__ float ldin(const void* p, long long i, int flag) {
  if (flag) {
    unsigned short b = ((const unsigned short*)p)[i];
    return __uint_as_float(((unsigned)b) << 16);
  }
  return ((const float*)p)[i];
}

// order-preserving f32 -> u32 (exact): monotone for all finite floats
__device__ __forceinline__ unsigned sortable(float v) {
  unsigned u = __float_as_uint(v);
  return (u & 0x80000000u) ? ~u : (u | 0x80000000u);
}

// wave-wide max of u32 via DPP reduction chain; uniform result via readlane 63.
__device__ __forceinline__ unsigned wave_max_u32(unsigned x) {
  unsigned t;
  t = (unsigned)__builtin_amdgcn_update_dpp(0, (int)x, 0x111, 0xF, 0xF, true); x = x > t ? x : t; // row_shr:1
  t = (unsigned)__builtin_amdgcn_update_dpp(0, (int)x, 0x112, 0xF, 0xF, true); x = x > t ? x : t; // row_shr:2
  t = (unsigned)__builtin_amdgcn_update_dpp(0, (int)x, 0x114, 0xF, 0xF, true); x = x > t ? x : t; // row_shr:4
  t = (unsigned)__builtin_amdgcn_update_dpp(0, (int)x, 0x118, 0xF, 0xF, true); x = x > t ? x : t; // row_shr:8
  t = (unsigned)__builtin_amdgcn_update_dpp(0, (int)x, 0x142, 0xF, 0xF, true); x = x > t ? x : t; // row_bcast:15
  t = (unsigned)__builtin_amdgcn_update_dpp(0, (int)x, 0x143, 0xF, 0xF, true); x = x > t ? x : t; // row_bcast:31
  return (unsigned)__builtin_amdgcn_readlane((int)x, 63);
}

// sorted-descending top-4 insert of (pd,idx); strict '>' keeps idx-ascending
// order among equal pds (stream feeds ascending idx) -> matches lax.top_k ties.
__device__ __forceinline__ void insert4p(unsigned pd, int idx,
    unsigned& p0, int& i0, unsigned& p1, int& i1,
    unsigned& p2, int& i2, unsigned& p3, int& i3) {
  bool b0 = pd > p0, b1 = pd > p1, b2 = pd > p2, b3 = pd > p3;
  p3 = b3 ? (b2 ? p2 : pd) : p3;  i3 = b3 ? (b2 ? i2 : idx) : i3;
  p2 = b2 ? (b1 ? p1 : pd) : p2;  i2 = b2 ? (b1 ? i1 : idx) : i2;
  p1 = b1 ? (b0 ? p0 : pd) : p1;  i1 = b1 ? (b0 ? i0 : idx) : i1;
  p0 = b0 ? pd : p0;              i0 = b0 ? idx : i0;
}

// ---------------- k0: dtype detect + convert inputs to f32 + fold BN params ----
__global__ __launch_bounds__(256) void k0_convert(InPtrs in, float* ws) {
  int flag = detect_bf16(in.p[0]);
  int gid = blockIdx.x * 256 + threadIdx.x;
  int stride = gridDim.x * 256;
  if (flag) {
    const ushort4* src = (const ushort4*)in.p[1];
    float4* dst = (float4*)(ws + WS_F);
    for (int i = gid; i < 262144; i += stride) {
      ushort4 s = src[i];
      dst[i] = make_float4(
        __uint_as_float(((unsigned)s.x) << 16), __uint_as_float(((unsigned)s.y) << 16),
        __uint_as_float(((unsigned)s.z) << 16), __uint_as_float(((unsigned)s.w) << 16));
    }
  } else {
    const float4* src = (const float4*)in.p[1];
    float4* dst = (float4*)(ws + WS_F);
    for (int i = gid; i < 262144; i += stride) dst[i] = src[i];
  }
  // W2 transpose: W2T[c][o] = W2[o][c]
  for (int i = gid; i < 16384; i += stride) {
    int c = i >> 6, o = i & 63;
    ws[WS_W2T + i] = ldin(in.p[8], o * 256 + c, flag);
  }
  // xyz + small weight matrices
  const int T0 = 24576;           // xyz end
  const int T1 = T0 + 384;        // w_mlp1 end
  const int T2 = T1 + 2048;       // w_down1 end
  const int T3 = T2 + 2048;       // w_down2 end
  const int T4 = T3 + 2048;       // w_up end (31104)
  for (int i = gid; i < T4; i += stride) {
    const void* src; int off, dst;
    if      (i < T0) { src = in.p[0];  off = i;      dst = WS_X   + off; }
    else if (i < T1) { src = in.p[2];  off = i - T0; dst = WS_W1  + off; }
    else if (i < T2) { src = in.p[14]; off = i - T1; dst = WS_WD1 + off; }
    else if (i < T3) { src = in.p[15]; off = i - T2; dst = WS_WD2 + off; }
    else             { src = in.p[16]; off = i - T3; dst = WS_WUP + off; }
    ws[dst] = ldin(src, off, flag);
  }
  if (blockIdx.x == 0) {
    int t = threadIdx.x;
    if (t < 64) {
      float b1 = ldin(in.p[3], t, flag), g1 = ldin(in.p[4], t, flag);
      float be1 = ldin(in.p[5], t, flag), m1 = ldin(in.p[6], t, flag), v1 = ldin(in.p[7], t, flag);
      float s1 = g1 / sqrtf(v1 + 1e-5f);
      ws[WS_S1 + t] = s1;
      ws[WS_C1 + t] = s1 * (b1 - m1) + be1;
      float b2 = ldin(in.p[9], t, flag), g2 = ldin(in.p[10], t, flag);
      float be2 = ldin(in.p[11], t, flag), m2 = ldin(in.p[12], t, flag), v2 = ldin(in.p[13], t, flag);
      float s2 = g2 / sqrtf(v2 + 1e-5f);
      ws[WS_S2 + t] = s2;
      ws[WS_C2 + t] = s2 * (b2 - m2) + be2;
    }
    if (t < 128) {
      float bu = ldin(in.p[17], t, flag), gu = ldin(in.p[18], t, flag);
      float beu = ldin(in.p[19], t, flag), mu = ldin(in.p[20], t, flag), vu = ldin(in.p[21], t, flag);
      float su = gu / sqrtf(vu + 1e-5f);
      ws[WS_SUP + t] = su;
      ws[WS_CUP + t] = su * (bu - mu) + beu;
    }
    if (t < 16) ws[WS_FCACC + t] = 0.f;
    if (t == 0) ((int*)ws)[WS_FLAG] = flag;
  }
}

// ---------------- k1: P,Q projections — no LDS, scalar W2T loads --------------
// 512 blocks; wave = 64 m-points x 4 o-channels (o uniform per wave -> s_load).
__global__ __launch_bounds__(256) void k1_pq(float* ws) {
  int t = threadIdx.x;
  int bid = blockIdx.x;              // 512 = 2b x 64mt x 4ot
  int b = bid >> 8;
  int mt = (bid >> 2) & 63;
  int ot = bid & 3;
  int w = __builtin_amdgcn_readfirstlane(t >> 6);
  int lane = t & 63;
  int o0 = ot * 16 + w * 4;          // wave-uniform
  int m = (mt << 6) + lane;
  const float* F = ws + WS_F + (long long)b * CC * NN;
  const float* W2T = ws + WS_W2T;
  float accP[4] = {0.f, 0.f, 0.f, 0.f}, accQ[4] = {0.f, 0.f, 0.f, 0.f};
#pragma unroll 4
  for (int c = 0; c < 128; ++c) {
    float f = F[c * NN + m];
#pragma unroll
    for (int j = 0; j < 4; ++j) {
      accP[j] = fmaf(W2T[c * 64 + o0 + j], f, accP[j]);
      accQ[j] = fmaf(W2T[(128 + c) * 64 + o0 + j], f, accQ[j]);
    }
  }
  const float* X = ws + WS_X + (long long)b * 3 * NN;
  float x0 = X[m], x1 = X[NN + m], x2 = X[2 * NN + m];
  const float* W1 = ws + WS_W1;
  float* P = ws + WS_P + ((long long)(b * NN + m)) * 128;
  float* Q = ws + WS_Q + ((long long)(b * NN + m)) * 128;
  float4 p1v, q1v, p2v, q2v;
#pragma unroll
  for (int j = 0; j < 4; ++j) {
    int o = o0 + j;
    float s1 = ws[WS_S1 + o], c1 = ws[WS_C1 + o];
    float px = fmaf(W1[o * 6 + 2], x2, fmaf(W1[o * 6 + 1], x1, W1[o * 6 + 0] * x0));
    float qx = fmaf(W1[o * 6 + 5], x2, fmaf(W1[o * 6 + 4], x1, W1[o * 6 + 3] * x0));
    (&p1v.x)[j] = s1 * px;
    (&q1v.x)[j] = fmaf(s1, qx - px, c1);
    float s2 = ws[WS_S2 + o], c2 = ws[WS_C2 + o];
    (&p2v.x)[j] = s2 * accP[j];
    (&q2v.x)[j] = fmaf(s2, accQ[j] - accP[j], c2);
  }
  *(float4*)(P + o0)      = p1v;
  *(float4*)(P + 64 + o0) = p2v;
  *(float4*)(Q + o0)      = q1v;
  *(float4*)(Q + 64 + o0) = q2v;
  if (ot == 0 && w == 0) {
    float xx = __fadd_rn(__fadd_rn(__fmul_rn(x0, x0), __fmul_rn(x1, x1)), __fmul_rn(x2, x2));
    ws[WS_XX + b * NN + m] = xx;
  }
}

// ------- k23: KNN top-20 (u32 keys + DPP wave-max) + gather + max-pool --------
__global__ __launch_bounds__(256) void k23_knn_fenc(float* ws) {
  int t = threadIdx.x;
  int w = t >> 6, lane = t & 63;
  int pt = blockIdx.x * 4 + w;                // 2048 blocks, 1 wave = 1 point
  int b = pt >> 12;
  int n = pt & (NN - 1);
  const float* X = ws + WS_X + (long long)b * 3 * NN;
  const float* XX = ws + WS_XX + (long long)b * NN;
  float xc0 = X[n], xc1 = X[NN + n], xc2 = X[2 * NN + n], xxn = XX[n];
  unsigned p0 = 0, p1 = 0, p2 = 0, p3 = 0;
  int i0 = 0, i1 = 0, i2 = 0, i3 = 0;
#pragma unroll 4
  for (int s = 0; s < 64; ++s) {
    int m = s * 64 + lane;
    float c0 = X[m], c1 = X[NN + m], c2 = X[2 * NN + m], xxm = XX[m];
    float inner = __fadd_rn(__fadd_rn(__fmul_rn(c0, xc0), __fmul_rn(c1, xc1)), __fmul_rn(c2, xc2));
    float pd = __fsub_rn(__fsub_rn(__fmul_rn(2.0f, inner), xxn), xxm);
    insert4p(sortable(pd), m, p0, i0, p1, i1, p2, i2, p3, i3);
  }
  unsigned long long used = 0;
  int nv = 4;
  int winner = 0;                             // lane r keeps round-r winner index
  for (int r = 0; r < KK; ++r) {
    unsigned spd = wave_max_u32(p0);          // max pd among heads (uniform)
    unsigned cand = (p0 == spd) ? (unsigned)(4095 - i0) : 0u;
    unsigned sidx = 4095u - wave_max_u32(cand); // min idx among ties (uniform)
    if (lane == r) winner = (int)sidx;
    if (p0 == spd && i0 == (int)sidx) {       // unique owner lane
      used |= 1ull << (i0 >> 6);
      p0 = p1; i0 = i1; p1 = p2; i1 = i2; p2 = p3; i2 = i3; p3 = 0; i3 = 0;
      if (--nv == 0) {                        // rare: lane supplied >=5 winners
        p0 = p1 = p2 = p3 = 0; i0 = i1 = i2 = i3 = 0;
#pragma unroll 1
        for (int s = 0; s < 64; ++s) {
          if (!((used >> s) & 1ull)) {
            int m = s * 64 + lane;
            float c0 = X[m], c1 = X[NN + m], c2 = X[2 * NN + m], xxm = XX[m];
            float inner = __fadd_rn(__fadd_rn(__fmul_rn(c0, xc0), __fmul_rn(c1, xc1)), __fmul_rn(c2, xc2));
            float pd = __fsub_rn(__fsub_rn(__fmul_rn(2.0f, inner), xxn), xxm);
            insert4p(sortable(pd), m, p0, i0, p1, i1, p2, i2, p3, i3);
          }
        }
        nv = 4;
      }
    }
  }
  // gather + max-pool
  const float* Q = ws + WS_Q + (long long)pt * 128;
  const float* Pb = ws + WS_P + (long long)b * NN * 128;
  float2 q = ((const float2*)Q)[lane];
  float mx0 = -3.4e38f, mx1 = -3.4e38f;
#pragma unroll
  for (int j = 0; j < KK; ++j) {
    int id = __shfl(winner, j);
    float2 p = ((const float2*)(Pb + (long long)id * 128))[lane];
    mx0 = fmaxf(mx0, p.x + q.x);
    mx1 = fmaxf(mx1, p.y + q.y);
  }
  float2 fe = make_float2(fmaxf(mx0, 0.f), fmaxf(mx1, 0.f));
  ((float2*)(ws + WS_FE + (long long)pt * 128))[lane] = fe;
}

// ---------------- k4: down-projections f1,f2 + f_space + f_channel accum ------
__global__ __launch_bounds__(256) void k4_down(float* ws) {
  __shared__ float ldsFE[8 * 128];
  __shared__ float ldsW[32 * 129];
  __shared__ float ldsFC[16];
  int t = threadIdx.x;
  int b = blockIdx.x >> 9;
  int n0 = (blockIdx.x & 511) << 3;
  for (int i = t; i < 8 * 128; i += 256) {
    int p = i >> 7, c = i & 127;
    ldsFE[i] = ws[WS_FE + (long long)(b * NN + n0 + p) * 128 + c];
  }
  for (int i = t; i < 32 * 128; i += 256) {
    int o = i >> 7, c = i & 127;
    ldsW[o * 129 + c] = (o < 16) ? ws[WS_WD1 + o * 128 + c] : ws[WS_WD2 + (o - 16) * 128 + c];
  }
  if (t < 16) ldsFC[t] = 0.f;
  __syncthreads();
  int p = t >> 5, oid = t & 31;
  float acc = 0.f;
#pragma unroll 8
  for (int c = 0; c < 128; ++c)
    acc = fmaf(ldsW[oid * 129 + c], ldsFE[p * 128 + c], acc);
  float v = fmaxf(acc, 0.f);
  ws[WS_F12 + (long long)(b * NN + n0 + p) * 32 + oid] = v;
  if (b == 0) {
    if (oid >= 16) {
      float s = v;
#pragma unroll
      for (int d = 1; d < 16; d <<= 1) s += __shfl_xor(s, d);
      if (oid == 16) ws[WS_FS + n0 + p] = s * 0.0625f;
    } else {
      atomicAdd(&ldsFC[oid], v);
    }
  }
  __syncthreads();
  if (b == 0 && t < 16) atomicAdd(ws + WS_FCACC + t, ldsFC[t]);
}

// ---------------- k5: outer-sqrt + up-proj + BN + Mish -> output --------------
__global__ __launch_bounds__(256) void k5_final(float* ws, float* outf, __hip_bfloat16* outb) {
  __shared__ float fin[16 * 16];
  int t = threadIdx.x;
  int g = t >> 4;        // 0..15 : output group of 8
  int p = t & 15;        // point within tile
  int b = blockIdx.x >> 8;
  int n0 = (blockIdx.x & 255) << 4;
  int n = n0 + p;
  int flag = ((const int*)ws)[WS_FLAG];
  {
    float fs = ws[WS_FS + n];
    float fc = ws[WS_FCACC + g] * (1.0f / NN);
    float f1v = ws[WS_F12 + (long long)(b * NN + n) * 32 + g];
    float f2v = ws[WS_F12 + (long long)(b * NN + n) * 32 + 16 + g];
    fin[p * 16 + g] = sqrtf(fc * fs + 1e-12f) + f1v + f2v;
  }
  __syncthreads();
  const float4* FE4 = (const float4*)(ws + WS_FE + (long long)(b * NN + n) * 128 + g * 8);
  float fev[8];
  {
    float4 a = FE4[0], c = FE4[1];
    fev[0] = a.x; fev[1] = a.y; fev[2] = a.z; fev[3] = a.w;
    fev[4] = c.x; fev[5] = c.y; fev[6] = c.z; fev[7] = c.w;
  }
#pragma unroll
  for (int j = 0; j < 8; ++j) {
    int o = g * 8 + j;
    float acc = 0.f;
#pragma unroll
    for (int c = 0; c < 16; ++c)
      acc = fmaf(ws[WS_WUP + o * 16 + c], fin[p * 16 + c], acc);
    float fo = fmaf(ws[WS_SUP + o], acc, ws[WS_CUP + o]);
    fo = fmaxf(fo, 0.f);
    float fl = fev[j] - fo;
    // Mish(x) = x*(u^2+2u)/(u^2+2u+2), u=e^x; exact for x<=15, y=x beyond
    float u = __expf(fl);
    float nmr = u * (u + 2.f);
    float y = fl * __fdividef(nmr, nmr + 2.f);
    if (fl > 15.f) y = fl;
    long long oi = ((long long)b * CC + o) * NN + n;
    if (flag) outb[oi] = __float2bfloat16(y);
    else      outf[oi] = y;
  }
}

extern "C" void kernel_launch(void* const* d_in, const int* in_sizes, int n_in,
                              void* d_out, int out_size, void* d_ws, size_t ws_size,
                              hipStream_t stream) {
  (void)in_sizes; (void)out_size; (void)ws_size;
  float* ws = (float*)d_ws;
  InPtrs ip;
  for (int i = 0; i < 22; ++i) ip.p[i] = (i < n_in) ? d_in[i] : nullptr;
  hipLaunchKernelGGL(k0_convert,   dim3(512),          dim3(256), 0, stream, ip, ws);
  hipLaunchKernelGGL(k1_pq,        dim3(512),          dim3(256), 0, stream, ws);
  hipLaunchKernelGGL(k23_knn_fenc, dim3(BB * NN / 4),  dim3(256), 0, stream, ws);
  hipLaunchKernelGGL(k4_down,      dim3(BB * NN / 8),  dim3(256), 0, stream, ws);
  hipLaunchKernelGGL(k5_final,     dim3(BB * NN / 16), dim3(256), 0, stream, ws,
                     (float*)d_out, (__hip_bfloat16*)d_out);
}